// Round 9
// baseline (261.335 us; speedup 1.0000x reference)
//
#include <hip/hip_runtime.h>
#include <math.h>

#define DIM      512
#define KC       8192     // codes
#define NR       8192     // rows
#define BM       256      // rows per block
#define BN       256      // codes per tile
#define NT       2        // code tiles per block
#define CHUNK    (BN*NT)  // 512 codes per block
#define NXB      (KC/CHUNK) // 16 partials per row
#define KT       (DIM/32) // 16 k-tiles of 32
#define EPS      0.125f   // margin below which we re-score exactly
#define MAXF     1024     // max flagged rows the rescue path covers
#define RCODES   512      // codes per rescue block-column (4 waves x 128)

typedef __attribute__((ext_vector_type(8))) _Float16 f16x8;
typedef __attribute__((ext_vector_type(4))) float f32x4;

#define AS1 __attribute__((address_space(1)))
#define AS3 __attribute__((address_space(3)))

// ---------------------------------------------------------------------------
// Pack: fp32 -> fp16 in fragment-tiled layout. Tile = 16 rows x 32 k, stored
// in MFMA lane order: lane = (row&15) + 16*kg holds elems k = kg*8..kg*8+7.
// ---------------------------------------------------------------------------
__global__ void pack_kernel(const float* __restrict__ X, const float* __restrict__ E,
                            _Float16* __restrict__ Xp, _Float16* __restrict__ Ep) {
    const float* src = blockIdx.y ? E : X;
    _Float16* dst = blockIdx.y ? Ep : Xp;
    const int tile = blockIdx.x * 4 + (threadIdx.x >> 6);
    const int lane = threadIdx.x & 63;
    const int rt = tile / KT, kt = tile % KT;
    const int row = rt * 16 + (lane & 15);
    const int k   = kt * 32 + (lane >> 4) * 8;
    const float4* p = reinterpret_cast<const float4*>(src + (size_t)row * DIM + k);
    const float4 a = p[0], b = p[1];
    f16x8 o;
    o[0] = (_Float16)a.x; o[1] = (_Float16)a.y; o[2] = (_Float16)a.z; o[3] = (_Float16)a.w;
    o[4] = (_Float16)b.x; o[5] = (_Float16)b.y; o[6] = (_Float16)b.z; o[7] = (_Float16)b.w;
    *reinterpret_cast<f16x8*>(dst + (size_t)tile * 512 + lane * 8) = o;
}

// ---------------------------------------------------------------------------
// e_sq[k] = sum_d E[k][d]^2 (fp32 exact, one wave per code). Zeroes fcount.
// ---------------------------------------------------------------------------
__global__ void esq_kernel(const float* __restrict__ E, float* __restrict__ e_sq,
                           int* __restrict__ fcount) {
    if (blockIdx.x == 0 && threadIdx.x == 0) *fcount = 0;
    const int wave = threadIdx.x >> 6;
    const int lane = threadIdx.x & 63;
    const int row  = blockIdx.x * 4 + wave;
    const float4* p = reinterpret_cast<const float4*>(E + (size_t)row * DIM) + lane * 2;
    float4 a = p[0], b = p[1];
    float s = a.x * a.x + a.y * a.y + a.z * a.z + a.w * a.w
            + b.x * b.x + b.y * b.y + b.z * b.z + b.w * b.w;
    #pragma unroll
    for (int off = 32; off > 0; off >>= 1) s += __shfl_down(s, off, 64);
    if (lane == 0) e_sq[row] = s;
}

// ---------------------------------------------------------------------------
// f16 MFMA scorer, R8 schedule (stage -> sync -> compute -> sync), scaled to
// 256x256 block tile: 8 waves (512 thr) as 4(wr) x 2(wc), wave tile 64x128.
// Staged bytes per MAC drops 33% vs 128x256 (the R4/R8-measured limiter).
// ---------------------------------------------------------------------------
__global__ __launch_bounds__(512, 2)
void vq_mfma_kernel(const _Float16* __restrict__ Xp, const _Float16* __restrict__ Ep,
                    const float* __restrict__ e_sq,
                    float* __restrict__ pbest, float* __restrict__ psec,
                    int* __restrict__ pidx)
{
    // f16 elems: A tiles [0, 16384) (32 KB), B tiles [16384, 32768) (32 KB)
    __shared__ _Float16 lds[32768];   // 64 KB

    const int tid  = threadIdx.x;
    const int lane = tid & 63;
    const int w    = tid >> 6;        // 0..7
    const int wr   = w >> 1;          // wave row quarter (0..3)
    const int wc   = w & 1;           // wave col half (0/1)

    // XCD-aware swizzle over 512 flat blocks: XCD c owns code-chunks
    // {2c, 2c+1} x all 32 row-blocks -> its E-slice stays L2-resident.
    const int bid = blockIdx.x;
    const int xcd = bid & 7, pos = bid >> 3;   // pos 0..63
    const int cx  = xcd * 2 + (pos >> 5);      // code-chunk 0..15
    const int ry  = pos & 31;                  // row-block 0..31
    const int row0  = ry * BM;
    const int cbase = cx * CHUNK;
    const int rtb  = row0 >> 4;                // global row-tile base (16 rows/tile)
    const int ctb0 = cbase >> 4;               // global code-tile base (nt=0)

    float s1[16], s2[16];
    int   i1[16];
    #pragma unroll
    for (int i = 0; i < 16; ++i) { s1[i] = -INFINITY; s2[i] = -INFINITY; i1[i] = 0; }

    for (int nt = 0; nt < NT; ++nt) {
        const int code0 = cbase + nt * BN;
        const int ctb = ctb0 + nt * 16;     // 16 code row-tiles per nt

        f32x4 acc[4][8];
        #pragma unroll
        for (int m = 0; m < 4; ++m)
            #pragma unroll
            for (int n = 0; n < 8; ++n)
                acc[m][n] = (f32x4){0.f, 0.f, 0.f, 0.f};

        for (int ks = 0; ks < 8; ++ks) {    // BK=64 steps
            const int kt2 = ks * 2;
            // ---- stage: 32 A-tiles + 32 B-tiles (1 KB each), 4+4 per wave
            #pragma unroll
            for (int i = 0; i < 4; ++i) {
                const int t = w * 4 + i;           // tile 0..31
                const int rt = t >> 1, ktl = t & 1;
                const _Float16* ga = Xp + (((size_t)(rtb + rt) * KT + kt2 + ktl) << 9) + lane * 8;
                __builtin_amdgcn_global_load_lds(
                    (const AS1 void*)ga, (AS3 void*)(lds + t * 512), 16, 0, 0);
                const _Float16* gb = Ep + (((size_t)(ctb + rt) * KT + kt2 + ktl) << 9) + lane * 8;
                __builtin_amdgcn_global_load_lds(
                    (const AS1 void*)gb, (AS3 void*)(lds + 16384 + t * 512), 16, 0, 0);
            }
            __syncthreads();

            // ---- compute: 2 kk x (12 ds_read_b128, 32 MFMA)
            #pragma unroll
            for (int kk = 0; kk < 2; ++kk) {
                f16x8 bfrag[8];
                #pragma unroll
                for (int n = 0; n < 8; ++n)
                    bfrag[n] = *reinterpret_cast<const f16x8*>(
                        lds + 16384 + ((wc * 8 + n) * 2 + kk) * 512 + lane * 8);
                #pragma unroll
                for (int m = 0; m < 4; ++m) {
                    const f16x8 afrag = *reinterpret_cast<const f16x8*>(
                        lds + ((wr * 4 + m) * 2 + kk) * 512 + lane * 8);
                    #pragma unroll
                    for (int n = 0; n < 8; ++n)
                        acc[m][n] = __builtin_amdgcn_mfma_f32_16x16x32_f16(
                            afrag, bfrag[n], acc[m][n], 0, 0, 0);
                }
            }
            __syncthreads();
        }

        // ---- fold this 256-code tile into running (best, second, idx) ----
        #pragma unroll
        for (int n = 0; n < 8; ++n) {
            const int code = code0 + wc * 128 + n * 16 + (lane & 15);
            const float esv = e_sq[code];          // L2-hot, twice per block
            #pragma unroll
            for (int m = 0; m < 4; ++m) {
                #pragma unroll
                for (int r = 0; r < 4; ++r) {
                    const float sc = fmaf(2.0f, acc[m][n][r], -esv);
                    const int slot = m * 4 + r;
                    if (sc > s1[slot]) { s2[slot] = s1[slot]; s1[slot] = sc; i1[slot] = code; }
                    else if (sc > s2[slot]) { s2[slot] = sc; }
                    else if (sc == s1[slot]) { s2[slot] = sc; }   // exact tie -> margin 0
                }
            }
        }
    }

    // ---- cross-lane reduce within each 16-lane col group ----
    #pragma unroll
    for (int slot = 0; slot < 16; ++slot) {
        #pragma unroll
        for (int mask = 1; mask < 16; mask <<= 1) {
            float t1 = __shfl_xor(s1[slot], mask, 64);
            float t2 = __shfl_xor(s2[slot], mask, 64);
            int   j1 = __shfl_xor(i1[slot], mask, 64);
            if (t1 > s1[slot]) { s2[slot] = fmaxf(s1[slot], t2); s1[slot] = t1; i1[slot] = j1; }
            else if (t1 == s1[slot]) { s2[slot] = fmaxf(s2[slot], fmaxf(t1, t2)); i1[slot] = min(i1[slot], j1); }
            else { s2[slot] = fmaxf(s2[slot], t1); }
        }
    }

    __syncthreads();   // all compute done before aliasing LDS
    float* reds1 = reinterpret_cast<float*>(&lds[0]);     // [BM][2]
    float* reds2 = reds1 + BM * 2;                        // [BM][2]
    int*   redi  = reinterpret_cast<int*>(reds2 + BM * 2);// [BM][2]

    if ((lane & 15) == 0) {
        #pragma unroll
        for (int m = 0; m < 4; ++m)
            #pragma unroll
            for (int r = 0; r < 4; ++r) {
                const int row = wr * 64 + m * 16 + (lane >> 4) * 4 + r;   // 0..255
                reds1[row * 2 + wc] = s1[m * 4 + r];
                reds2[row * 2 + wc] = s2[m * 4 + r];
                redi [row * 2 + wc] = i1[m * 4 + r];
            }
    }
    __syncthreads();

    if (tid < BM) {
        float a1 = reds1[tid * 2 + 0], a2 = reds2[tid * 2 + 0]; int ai = redi[tid * 2 + 0];
        const float b1 = reds1[tid * 2 + 1], b2 = reds2[tid * 2 + 1]; const int bi = redi[tid * 2 + 1];
        if (b1 > a1)       { a2 = fmaxf(a1, b2); a1 = b1; ai = bi; }
        else if (b1 == a1) { a2 = fmaxf(a2, fmaxf(b1, b2)); ai = min(ai, bi); }
        else               { a2 = fmaxf(a2, b1); }
        const int row = row0 + tid;
        pbest[(size_t)row * NXB + cx] = a1;
        psec [(size_t)row * NXB + cx] = a2;
        pidx [(size_t)row * NXB + cx] = ai;
    }
}

// ---------------------------------------------------------------------------
// Merge NXB partials per row; compact rows with small margin into frow[].
// ---------------------------------------------------------------------------
__global__ void reduce_kernel(const float* __restrict__ pbest, const float* __restrict__ psec,
                              const int* __restrict__ pidx,
                              int* __restrict__ final_idx,
                              int* __restrict__ fcount, int* __restrict__ frow,
                              int* __restrict__ fslot)
{
    const int row = blockIdx.x * 256 + threadIdx.x;
    float s1 = -INFINITY, s2 = -INFINITY; int i1 = 0;
    #pragma unroll
    for (int j = 0; j < NXB; ++j) {
        const float t1 = pbest[(size_t)row * NXB + j];
        const float t2 = psec [(size_t)row * NXB + j];
        const int   j1 = pidx [(size_t)row * NXB + j];
        if (t1 > s1)       { s2 = fmaxf(s1, t2); s1 = t1; i1 = j1; }
        else if (t1 == s1) { s2 = fmaxf(s2, fmaxf(t1, t2)); i1 = min(i1, j1); }
        else               { s2 = fmaxf(s2, t1); }
    }
    final_idx[row] = i1;
    int slot = -1;
    if (s1 - s2 < EPS) {
        const int f = atomicAdd(fcount, 1);
        if (f < MAXF) { frow[f] = row; slot = f; }
    }
    fslot[row] = slot;
}

// ---------------------------------------------------------------------------
// Exact fp32 rescore: grid (256, 16); block x strides the flagged-row list,
// block y picks the 512-code column; wave per code-group, lanes split dims.
// ---------------------------------------------------------------------------
__global__ __launch_bounds__(256)
void rescue_kernel(const float* __restrict__ X, const float* __restrict__ E,
                   const float* __restrict__ e_sq,
                   const int* __restrict__ fcount, const int* __restrict__ frow,
                   float* __restrict__ rbest, int* __restrict__ ridx)
{
    const int nf0 = *fcount;
    const int nf  = nf0 < MAXF ? nf0 : MAXF;
    const int lane = threadIdx.x & 63;
    const int w    = threadIdx.x >> 6;

    for (int f = blockIdx.x; f < nf; f += 256) {
        const int row = frow[f];
        const float4* xp = reinterpret_cast<const float4*>(X + (size_t)row * DIM) + lane * 2;
        const float4 x0 = xp[0], x1 = xp[1];

        const int c0 = blockIdx.y * RCODES + w * (RCODES / 4);
        float best = -INFINITY; int bi = 0;
        for (int c = c0; c < c0 + RCODES / 4; ++c) {
            const float4* ep = reinterpret_cast<const float4*>(E + (size_t)c * DIM) + lane * 2;
            const float4 e0 = ep[0], e1 = ep[1];
            float dot = x0.x * e0.x;
            dot = fmaf(x0.y, e0.y, dot);
            dot = fmaf(x0.z, e0.z, dot);
            dot = fmaf(x0.w, e0.w, dot);
            dot = fmaf(x1.x, e1.x, dot);
            dot = fmaf(x1.y, e1.y, dot);
            dot = fmaf(x1.z, e1.z, dot);
            dot = fmaf(x1.w, e1.w, dot);
            #pragma unroll
            for (int mask = 1; mask < 64; mask <<= 1) dot += __shfl_xor(dot, mask, 64);
            const float s = fmaf(2.f, dot, -e_sq[c]);
            if (s > best) { best = s; bi = c; }    // ascending c: first occurrence wins
        }
        if (lane == 0) {
            const int p = f * 64 + blockIdx.y * 4 + w;
            rbest[p] = best; ridx[p] = bi;
        }
    }
}

// ---------------------------------------------------------------------------
// Final index (rescued rows merge their 64 partials), write index + gather.
// Fully overwrites d_out (which held the packed fp16 planes until now).
// ---------------------------------------------------------------------------
__global__ void gather_kernel(const int* __restrict__ final_idx,
                              const int* __restrict__ fslot,
                              const float* __restrict__ rbest, const int* __restrict__ ridx,
                              const float* __restrict__ E,
                              float* __restrict__ out_q, float* __restrict__ out_i)
{
    const int row = blockIdx.x;
    __shared__ int s_bi;
    if (threadIdx.x < 64) {
        const int slot = fslot[row];
        int bi;
        if (slot >= 0) {
            float b = rbest[slot * 64 + threadIdx.x];
            bi = ridx[slot * 64 + threadIdx.x];
            #pragma unroll
            for (int mask = 1; mask < 64; mask <<= 1) {
                const float ob = __shfl_xor(b, mask, 64);
                const int   oi = __shfl_xor(bi, mask, 64);
                if (ob > b || (ob == b && oi < bi)) { b = ob; bi = oi; }
            }
        } else {
            bi = final_idx[row];
        }
        if (threadIdx.x == 0) { s_bi = bi; out_i[row] = (float)bi; }
    }
    __syncthreads();
    const int bi = s_bi;
    const float4* src = reinterpret_cast<const float4*>(E + (size_t)bi * DIM);
    float4* dst = reinterpret_cast<float4*>(out_q + (size_t)row * DIM);
    dst[threadIdx.x] = src[threadIdx.x];
}

// ---------------------------------------------------------------------------
extern "C" void kernel_launch(void* const* d_in, const int* in_sizes, int n_in,
                              void* d_out, int out_size, void* d_ws, size_t ws_size,
                              hipStream_t stream) {
    const float* X = (const float*)d_in[0];   // [8192, 512]
    const float* E = (const float*)d_in[1];   // [8192, 512]

    float* out_q = (float*)d_out;                         // [8192, 512]
    float* out_i = (float*)d_out + (size_t)NR * DIM;      // [8192]

    // Packed fp16 planes live in d_out's space (16 MB of 16.03 MB);
    // gather_kernel fully overwrites d_out at the end of every launch.
    _Float16* Xp = (_Float16*)d_out;                      // 8 MB
    _Float16* Ep = Xp + (size_t)NR * DIM;                 // 8 MB

    float* e_sq      = (float*)d_ws;                      // 8192 f
    float* pbest     = e_sq + KC;                         // 8192*16 f
    float* psec      = pbest + (size_t)NR * NXB;          // 8192*16 f
    int*   pidx      = (int*)(psec + (size_t)NR * NXB);   // 8192*16 i
    int*   final_idx = pidx + (size_t)NR * NXB;           // 8192 i
    int*   fcount    = final_idx + NR;                    // 1 i
    int*   frow      = fcount + 1;                        // MAXF i
    int*   fslot     = frow + MAXF;                       // 8192 i
    float* rbest     = (float*)(fslot + NR);              // MAXF*64 f
    int*   ridx      = (int*)(rbest + MAXF * 64);         // MAXF*64 i

    hipLaunchKernelGGL(esq_kernel, dim3(KC / 4), dim3(256), 0, stream, E, e_sq, fcount);

    hipLaunchKernelGGL(pack_kernel, dim3(NR * DIM / (16 * 32) / 4, 2), dim3(256), 0, stream,
                       X, E, Xp, Ep);

    hipLaunchKernelGGL(vq_mfma_kernel, dim3(NXB * (NR / BM)), dim3(512), 0, stream,
                       Xp, Ep, e_sq, pbest, psec, pidx);

    hipLaunchKernelGGL(reduce_kernel, dim3(NR / 256), dim3(256), 0, stream,
                       pbest, psec, pidx, final_idx, fcount, frow, fslot);

    hipLaunchKernelGGL(rescue_kernel, dim3(256, KC / RCODES), dim3(256), 0, stream,
                       X, E, e_sq, fcount, frow, rbest, ridx);

    hipLaunchKernelGGL(gather_kernel, dim3(NR), dim3(128), 0, stream,
                       final_idx, fslot, rbest, ridx, E, out_q, out_i);
}

// Round 10
// 224.519 us; speedup vs baseline: 1.1640x; 1.1640x over previous
//
#include <hip/hip_runtime.h>
#include <math.h>

#define DIM      512
#define KC       8192     // codes
#define NR       8192     // rows
#define BM       128      // rows per block
#define BN       256      // codes per tile
#define NT       2        // code tiles per block
#define CHUNK    (BN*NT)  // 512 codes per block
#define NXB      (KC/CHUNK) // 16 partials per row
#define KT       (DIM/32) // 16 k-tiles of 32
#define EPS      0.125f   // margin below which we re-score exactly
#define MAXW     16384    // worklist capacity (80x expected ~200 entries)

typedef __attribute__((ext_vector_type(8))) _Float16 f16x8;
typedef __attribute__((ext_vector_type(4))) float f32x4;

#define AS1 __attribute__((address_space(1)))
#define AS3 __attribute__((address_space(3)))

// orderable key for float: monotone f -> u32
static __device__ __forceinline__ unsigned fkey(float f) {
    unsigned b = __float_as_uint(f);
    return (b & 0x80000000u) ? ~b : (b | 0x80000000u);
}

// ---------------------------------------------------------------------------
// Pack: fp32 -> fp16 in fragment-tiled layout. Tile = 16 rows x 32 k, stored
// in MFMA lane order: lane = (row&15) + 16*kg holds elems k = kg*8..kg*8+7.
// ---------------------------------------------------------------------------
__global__ void pack_kernel(const float* __restrict__ X, const float* __restrict__ E,
                            _Float16* __restrict__ Xp, _Float16* __restrict__ Ep) {
    const float* src = blockIdx.y ? E : X;
    _Float16* dst = blockIdx.y ? Ep : Xp;
    const int tile = blockIdx.x * 4 + (threadIdx.x >> 6);
    const int lane = threadIdx.x & 63;
    const int rt = tile / KT, kt = tile % KT;
    const int row = rt * 16 + (lane & 15);
    const int k   = kt * 32 + (lane >> 4) * 8;
    const float4* p = reinterpret_cast<const float4*>(src + (size_t)row * DIM + k);
    const float4 a = p[0], b = p[1];
    f16x8 o;
    o[0] = (_Float16)a.x; o[1] = (_Float16)a.y; o[2] = (_Float16)a.z; o[3] = (_Float16)a.w;
    o[4] = (_Float16)b.x; o[5] = (_Float16)b.y; o[6] = (_Float16)b.z; o[7] = (_Float16)b.w;
    *reinterpret_cast<f16x8*>(dst + (size_t)tile * 512 + lane * 8) = o;
}

// ---------------------------------------------------------------------------
// e_sq[k] = sum_d E[k][d]^2 (fp32 exact, one wave per code). Zeroes fcount.
// ---------------------------------------------------------------------------
__global__ void esq_kernel(const float* __restrict__ E, float* __restrict__ e_sq,
                           int* __restrict__ fcount) {
    if (blockIdx.x == 0 && threadIdx.x == 0) *fcount = 0;
    const int wave = threadIdx.x >> 6;
    const int lane = threadIdx.x & 63;
    const int row  = blockIdx.x * 4 + wave;
    const float4* p = reinterpret_cast<const float4*>(E + (size_t)row * DIM) + lane * 2;
    float4 a = p[0], b = p[1];
    float s = a.x * a.x + a.y * a.y + a.z * a.z + a.w * a.w
            + b.x * b.x + b.y * b.y + b.z * b.z + b.w * b.w;
    #pragma unroll
    for (int off = 32; off > 0; off >>= 1) s += __shfl_down(s, off, 64);
    if (lane == 0) e_sq[row] = s;
}

// ---------------------------------------------------------------------------
// f16 MFMA scorer — R8 champion config, unchanged. 4 waves as 2(wr) x 2(wc),
// per wave 4m x 8n fragments of 16x16x32 -> block tile 128 x 256, BK=64.
// ---------------------------------------------------------------------------
__global__ __launch_bounds__(256, 2)
void vq_mfma_kernel(const _Float16* __restrict__ Xp, const _Float16* __restrict__ Ep,
                    const float* __restrict__ e_sq,
                    float* __restrict__ pbest, float* __restrict__ psec,
                    int* __restrict__ pidx)
{
    // f16 elems: A tiles [0, 8192) (16 KB), B tiles [8192, 24576) (32 KB)
    __shared__ _Float16 lds[24576];   // 48 KB

    const int tid  = threadIdx.x;
    const int lane = tid & 63;
    const int w    = tid >> 6;
    const int wr   = w >> 1;          // wave row half (0/1)
    const int wc   = w & 1;           // wave col half (0/1)

    // XCD-aware swizzle over 1024 flat blocks.
    const int bid = blockIdx.x;
    const int xcd = bid & 7, pos = bid >> 3;
    const int cx  = xcd * 2 + (pos >> 6);   // code-chunk 0..15
    const int ry  = pos & 63;               // row-block 0..63
    const int row0  = ry * BM;
    const int cbase = cx * CHUNK;
    const int rtb  = row0 >> 4;             // global row-tile base
    const int ctb0 = cbase >> 4;            // global code-tile base (nt=0)

    float s1[16], s2[16];
    int   i1[16];
    #pragma unroll
    for (int i = 0; i < 16; ++i) { s1[i] = -INFINITY; s2[i] = -INFINITY; i1[i] = 0; }

    for (int nt = 0; nt < NT; ++nt) {
        const int code0 = cbase + nt * BN;
        const int ctb = ctb0 + nt * 16;     // 16 code row-tiles per nt

        f32x4 acc[4][8];
        #pragma unroll
        for (int m = 0; m < 4; ++m)
            #pragma unroll
            for (int n = 0; n < 8; ++n)
                acc[m][n] = (f32x4){0.f, 0.f, 0.f, 0.f};

        for (int ks = 0; ks < 8; ++ks) {    // BK=64 steps
            const int kt2 = ks * 2;
            // ---- stage: 16 A-tiles (4/wave) + 32 B-tiles (8/wave), 1 KB each
            #pragma unroll
            for (int i = 0; i < 4; ++i) {
                const int t = w * 4 + i;           // A tile 0..15
                const int rt = t >> 1, ktl = t & 1;
                const _Float16* gp = Xp + (((size_t)(rtb + rt) * KT + kt2 + ktl) << 9) + lane * 8;
                __builtin_amdgcn_global_load_lds(
                    (const AS1 void*)gp, (AS3 void*)(lds + t * 512), 16, 0, 0);
            }
            #pragma unroll
            for (int j = 0; j < 8; ++j) {
                const int b = w * 8 + j;           // B tile 0..31
                const int rt = b >> 1, ktl = b & 1;
                const _Float16* gp = Ep + (((size_t)(ctb + rt) * KT + kt2 + ktl) << 9) + lane * 8;
                __builtin_amdgcn_global_load_lds(
                    (const AS1 void*)gp, (AS3 void*)(lds + 8192 + b * 512), 16, 0, 0);
            }
            __syncthreads();

            // ---- compute: 2 kk x (12 ds_read_b128, 32 MFMA)
            #pragma unroll
            for (int kk = 0; kk < 2; ++kk) {
                f16x8 bfrag[8];
                #pragma unroll
                for (int n = 0; n < 8; ++n)
                    bfrag[n] = *reinterpret_cast<const f16x8*>(
                        lds + 8192 + ((wc * 8 + n) * 2 + kk) * 512 + lane * 8);
                #pragma unroll
                for (int m = 0; m < 4; ++m) {
                    const f16x8 afrag = *reinterpret_cast<const f16x8*>(
                        lds + ((wr * 4 + m) * 2 + kk) * 512 + lane * 8);
                    #pragma unroll
                    for (int n = 0; n < 8; ++n)
                        acc[m][n] = __builtin_amdgcn_mfma_f32_16x16x32_f16(
                            afrag, bfrag[n], acc[m][n], 0, 0, 0);
                }
            }
            __syncthreads();
        }

        // ---- fold this 256-code tile into running (best, second, idx) ----
        #pragma unroll
        for (int n = 0; n < 8; ++n) {
            const int code = code0 + wc * 128 + n * 16 + (lane & 15);
            const float esv = e_sq[code];          // L2-hot, twice per block
            #pragma unroll
            for (int m = 0; m < 4; ++m) {
                #pragma unroll
                for (int r = 0; r < 4; ++r) {
                    const float sc = fmaf(2.0f, acc[m][n][r], -esv);
                    const int slot = m * 4 + r;
                    if (sc > s1[slot]) { s2[slot] = s1[slot]; s1[slot] = sc; i1[slot] = code; }
                    else if (sc > s2[slot]) { s2[slot] = sc; }
                    else if (sc == s1[slot]) { s2[slot] = sc; }   // exact tie -> margin 0
                }
            }
        }
    }

    // ---- cross-lane reduce within each 16-lane col group ----
    #pragma unroll
    for (int slot = 0; slot < 16; ++slot) {
        #pragma unroll
        for (int mask = 1; mask < 16; mask <<= 1) {
            float t1 = __shfl_xor(s1[slot], mask, 64);
            float t2 = __shfl_xor(s2[slot], mask, 64);
            int   j1 = __shfl_xor(i1[slot], mask, 64);
            if (t1 > s1[slot]) { s2[slot] = fmaxf(s1[slot], t2); s1[slot] = t1; i1[slot] = j1; }
            else if (t1 == s1[slot]) { s2[slot] = fmaxf(s2[slot], fmaxf(t1, t2)); i1[slot] = min(i1[slot], j1); }
            else { s2[slot] = fmaxf(s2[slot], t1); }
        }
    }

    __syncthreads();   // all compute done before aliasing LDS
    float* reds1 = reinterpret_cast<float*>(&lds[0]);     // [BM][2]
    float* reds2 = reds1 + BM * 2;                        // [BM][2]
    int*   redi  = reinterpret_cast<int*>(reds2 + BM * 2);// [BM][2]

    if ((lane & 15) == 0) {
        #pragma unroll
        for (int m = 0; m < 4; ++m)
            #pragma unroll
            for (int r = 0; r < 4; ++r) {
                const int row = wr * 64 + m * 16 + (lane >> 4) * 4 + r;
                reds1[row * 2 + wc] = s1[m * 4 + r];
                reds2[row * 2 + wc] = s2[m * 4 + r];
                redi [row * 2 + wc] = i1[m * 4 + r];
            }
    }
    __syncthreads();

    if (tid < BM) {
        float a1 = reds1[tid * 2 + 0], a2 = reds2[tid * 2 + 0]; int ai = redi[tid * 2 + 0];
        const float b1 = reds1[tid * 2 + 1], b2 = reds2[tid * 2 + 1]; const int bi = redi[tid * 2 + 1];
        if (b1 > a1)       { a2 = fmaxf(a1, b2); a1 = b1; ai = bi; }
        else if (b1 == a1) { a2 = fmaxf(a2, fmaxf(b1, b2)); ai = min(ai, bi); }
        else               { a2 = fmaxf(a2, b1); }
        const int row = row0 + tid;
        pbest[(size_t)row * NXB + cx] = a1;
        psec [(size_t)row * NXB + cx] = a2;
        pidx [(size_t)row * NXB + cx] = ai;
    }
}

// ---------------------------------------------------------------------------
// Merge NXB partials per row. Rows with small global margin are flagged and
// emit (row, chunk) worklist entries for every chunk whose pbest could hold
// the exact winner (pbest_j >= s1 - EPS).
// ---------------------------------------------------------------------------
__global__ void reduce_kernel(const float* __restrict__ pbest, const float* __restrict__ psec,
                              const int* __restrict__ pidx,
                              int* __restrict__ final_idx, int* __restrict__ flags,
                              int* __restrict__ fcount, int* __restrict__ wlist,
                              unsigned long long* __restrict__ rkey)
{
    const int row = blockIdx.x * 256 + threadIdx.x;
    float pb[NXB];
    float s1 = -INFINITY, s2 = -INFINITY; int i1 = 0;
    #pragma unroll
    for (int j = 0; j < NXB; ++j) {
        const float t1 = pbest[(size_t)row * NXB + j];
        const float t2 = psec [(size_t)row * NXB + j];
        const int   j1 = pidx [(size_t)row * NXB + j];
        pb[j] = t1;
        if (t1 > s1)       { s2 = fmaxf(s1, t2); s1 = t1; i1 = j1; }
        else if (t1 == s1) { s2 = fmaxf(s2, fmaxf(t1, t2)); i1 = min(i1, j1); }
        else               { s2 = fmaxf(s2, t1); }
    }
    final_idx[row] = i1;
    int fl = 0;
    if (s1 - s2 < EPS) {
        fl = 1;
        rkey[row] = 0ULL;
        #pragma unroll
        for (int j = 0; j < NXB; ++j) {
            if (pb[j] >= s1 - EPS) {
                const int p = atomicAdd(fcount, 1);
                if (p < MAXW) wlist[p] = (row << 4) | j;
            }
        }
    }
    flags[row] = fl;
}

// ---------------------------------------------------------------------------
// Exact fp32 rescore over worklist chunks only. One block per entry
// (grid-strided): 4 waves x 128 codes, lanes split the 512 dims (coalesced).
// Merge via atomicMax on packed (float-key, 8191-idx): order-independent,
// equal exact scores tie-break to MIN index (summation order is fixed ->
// bitwise-identical scores across blocks).
// ---------------------------------------------------------------------------
__global__ __launch_bounds__(256)
void rescue_kernel(const float* __restrict__ X, const float* __restrict__ E,
                   const float* __restrict__ e_sq,
                   const int* __restrict__ fcount, const int* __restrict__ wlist,
                   unsigned long long* __restrict__ rkey)
{
    const int nw0 = *fcount;
    const int nw  = nw0 < MAXW ? nw0 : MAXW;
    const int lane = threadIdx.x & 63;
    const int w    = threadIdx.x >> 6;
    __shared__ float rb[4];
    __shared__ int   ri[4];

    for (int e = blockIdx.x; e < nw; e += gridDim.x) {
        const int ent = wlist[e];
        const int row = ent >> 4;
        const int j   = ent & 15;

        const float4* xp = reinterpret_cast<const float4*>(X + (size_t)row * DIM) + lane * 2;
        const float4 x0 = xp[0], x1 = xp[1];

        const int c0 = j * CHUNK + w * (CHUNK / 4);
        float best = -INFINITY; int bi = 0;
        for (int c = c0; c < c0 + CHUNK / 4; ++c) {
            const float4* ep = reinterpret_cast<const float4*>(E + (size_t)c * DIM) + lane * 2;
            const float4 e0 = ep[0], e1 = ep[1];
            float dot = x0.x * e0.x;
            dot = fmaf(x0.y, e0.y, dot);
            dot = fmaf(x0.z, e0.z, dot);
            dot = fmaf(x0.w, e0.w, dot);
            dot = fmaf(x1.x, e1.x, dot);
            dot = fmaf(x1.y, e1.y, dot);
            dot = fmaf(x1.z, e1.z, dot);
            dot = fmaf(x1.w, e1.w, dot);
            #pragma unroll
            for (int mask = 1; mask < 64; mask <<= 1) dot += __shfl_xor(dot, mask, 64);
            const float s = fmaf(2.f, dot, -e_sq[c]);
            if (s > best) { best = s; bi = c; }    // ascending c: first occurrence wins
        }
        if (lane == 0) { rb[w] = best; ri[w] = bi; }
        __syncthreads();
        if (threadIdx.x == 0) {
            float b = rb[0]; int bbi = ri[0];
            #pragma unroll
            for (int q = 1; q < 4; ++q) {
                if (rb[q] > b || (rb[q] == b && ri[q] < bbi)) { b = rb[q]; bbi = ri[q]; }
            }
            const unsigned long long pk =
                ((unsigned long long)fkey(b) << 32) | (unsigned)(8191 - bbi);
            atomicMax(&rkey[row], pk);
        }
        __syncthreads();   // protect rb/ri before next entry
    }
}

// ---------------------------------------------------------------------------
// Final index (rescued rows unpack their atomicMax key), write index + gather.
// Fully overwrites d_out (which held the packed fp16 planes until now).
// ---------------------------------------------------------------------------
__global__ void gather_kernel(const int* __restrict__ final_idx,
                              const int* __restrict__ flags,
                              const unsigned long long* __restrict__ rkey,
                              const float* __restrict__ E,
                              float* __restrict__ out_q, float* __restrict__ out_i)
{
    const int row = blockIdx.x;
    __shared__ int s_bi;
    if (threadIdx.x == 0) {
        int bi;
        if (flags[row]) {
            const unsigned long long pk = rkey[row];
            bi = 8191 - (int)(pk & 0xFFFFFFFFull);
        } else {
            bi = final_idx[row];
        }
        s_bi = bi;
        out_i[row] = (float)bi;
    }
    __syncthreads();
    const int bi = s_bi;
    const float4* src = reinterpret_cast<const float4*>(E + (size_t)bi * DIM);
    float4* dst = reinterpret_cast<float4*>(out_q + (size_t)row * DIM);
    dst[threadIdx.x] = src[threadIdx.x];
}

// ---------------------------------------------------------------------------
extern "C" void kernel_launch(void* const* d_in, const int* in_sizes, int n_in,
                              void* d_out, int out_size, void* d_ws, size_t ws_size,
                              hipStream_t stream) {
    const float* X = (const float*)d_in[0];   // [8192, 512]
    const float* E = (const float*)d_in[1];   // [8192, 512]

    float* out_q = (float*)d_out;                         // [8192, 512]
    float* out_i = (float*)d_out + (size_t)NR * DIM;      // [8192]

    // Packed fp16 planes live in d_out's space (16 MB of 16.03 MB);
    // gather_kernel fully overwrites d_out at the end of every launch.
    _Float16* Xp = (_Float16*)d_out;                      // 8 MB
    _Float16* Ep = Xp + (size_t)NR * DIM;                 // 8 MB

    // ws layout (rkey first for 8-byte alignment): ~1.76 MB total
    unsigned long long* rkey = (unsigned long long*)d_ws; // NR u64 (64 KB)
    float* e_sq      = (float*)(rkey + NR);               // 8192 f
    float* pbest     = e_sq + KC;                         // 8192*16 f
    float* psec      = pbest + (size_t)NR * NXB;          // 8192*16 f
    int*   pidx      = (int*)(psec + (size_t)NR * NXB);   // 8192*16 i
    int*   final_idx = pidx + (size_t)NR * NXB;           // 8192 i
    int*   flags     = final_idx + NR;                    // 8192 i
    int*   wlist     = flags + NR;                        // MAXW i (64 KB)
    int*   fcount    = wlist + MAXW;                      // 1 i

    hipLaunchKernelGGL(esq_kernel, dim3(KC / 4), dim3(256), 0, stream, E, e_sq, fcount);

    hipLaunchKernelGGL(pack_kernel, dim3(NR * DIM / (16 * 32) / 4, 2), dim3(256), 0, stream,
                       X, E, Xp, Ep);

    hipLaunchKernelGGL(vq_mfma_kernel, dim3(NXB * (NR / BM)), dim3(256), 0, stream,
                       Xp, Ep, e_sq, pbest, psec, pidx);

    hipLaunchKernelGGL(reduce_kernel, dim3(NR / 256), dim3(256), 0, stream,
                       pbest, psec, pidx, final_idx, flags, fcount, wlist, rkey);

    hipLaunchKernelGGL(rescue_kernel, dim3(1024), dim3(256), 0, stream,
                       X, E, e_sq, fcount, wlist, rkey);

    hipLaunchKernelGGL(gather_kernel, dim3(NR), dim3(128), 0, stream,
                       final_idx, flags, rkey, E, out_q, out_i);
}